// Round 1
// baseline (517.094 us; speedup 1.0000x reference)
//
#include <hip/hip_runtime.h>
#include <math.h>

// Problem constants (reference: B=8, C=32, O=32, H=256, W=256, K=5, pad=2)
constexpr int IMG_H = 256;
constexpr int IMG_W = 256;
constexpr int NB = 8;
constexpr int NC = 32;
constexpr int NO = 32;

constexpr int TH = 8;    // tile height
constexpr int TW = 16;   // tile width
constexpr int CG = 16;   // channels staged per group (2 groups)
constexpr int RH = TH + 4;  // region height (halo 2)
constexpr int RW = TW + 4;  // region width
constexpr int NPX = TH * TW; // 128 pixels per tile

#define EPSV 1e-20f

__device__ __forceinline__ float rcpf_(float x) { return __builtin_amdgcn_rcpf(x); }
__device__ __forceinline__ float softplusf_(float x) {
  // stable log1p(exp(x)) = max(x,0) + log1p(exp(-|x|))
  return fmaxf(x, 0.0f) + log1pf(expf(-fabsf(x)));
}

// ws layout (floats): [0..31] wp, [32..831] sw (c-major, 25/ch),
// [832..1855] cwT[c][o] (transposed), [1856] sum(sw), [1857] sum(cw)
__global__ void weights_kernel(const float* __restrict__ wp_raw,
                               const float* __restrict__ sw_raw,
                               const float* __restrict__ cw_raw,
                               float* __restrict__ ws) {
  __shared__ float red[256];
  const int t = threadIdx.x;
  if (t < 32) ws[t] = softplusf_(wp_raw[t]);
  float ssum = 0.f;
  for (int i = t; i < NC * 25; i += 256) {
    float v = softplusf_(sw_raw[i]);
    ws[32 + i] = v;
    ssum += v;
  }
  float csum = 0.f;
  for (int i = t; i < NO * NC; i += 256) {
    float v = softplusf_(cw_raw[i]);
    int o = i >> 5, c = i & 31;
    ws[832 + c * NO + o] = v;  // transposed: [c][o]
    csum += v;
  }
  red[t] = ssum; __syncthreads();
  for (int off = 128; off; off >>= 1) { if (t < off) red[t] += red[t + off]; __syncthreads(); }
  const float S_sw = red[0];
  __syncthreads();
  red[t] = csum; __syncthreads();
  for (int off = 128; off; off >>= 1) { if (t < off) red[t] += red[t + off]; __syncthreads(); }
  if (t == 0) { ws[1856] = S_sw; ws[1857] = red[0]; }
}

__global__ __launch_bounds__(256) void fused_kernel(
    const float* __restrict__ dp, const float* __restrict__ cdp,
    const float* __restrict__ gxp, const float* __restrict__ cgxp,
    const float* __restrict__ ws, const float* __restrict__ bias,
    float* __restrict__ out) {
  // 63,488 B static LDS -> 2 blocks/CU
  __shared__ __align__(16) float Pbuf[CG * RH * RW];  // cgx_prop region
  __shared__ __align__(16) float Vbuf[CG * RH * RW];  // cgx_prop*gx_prop region
  __shared__ __align__(16) float Sarr[NC * NPX];      // cgx_s per (c, px)
  __shared__ __align__(16) float Uarr[NC * NPX];      // cgx_s*gx_s per (c, px)

  const int t = threadIdx.x;
  const int wt = blockIdx.x, ht = blockIdx.y, b = blockIdx.z;
  const int h0 = ht * TH, w0t = wt * TW;

  const float S_sw = ws[1856];
  const float S_cw = ws[1857];
  const float inv_Ssw = rcpf_(S_sw);
  const float inv_Scw = rcpf_(S_cw);
  const float* __restrict__ swp = ws + 32;
  const float* __restrict__ cwT = ws + 832;

  // depthwise task mapping: (w-run of 8, row, channel-in-group)
  const int run = t & 1;
  const int hh = (t >> 1) & 7;
  const int clt = t >> 4;
  const int w0 = run * 8;

  for (int g = 0; g < 2; ++g) {
    __syncthreads();
    // ---- stage P,V for channels [g*CG, g*CG+CG), region RH x RW (halo 2) ----
    for (int k = 0; k < (CG * RH * RW) / 256; ++k) {
      int i = t + k * 256;
      int cl = i / (RH * RW);
      int rem = i - cl * (RH * RW);
      int rr = rem / RW;
      int col = rem - rr * RW;
      int cgl = g * CG + cl;
      int gh = h0 + rr - 2;
      int gw = w0t + col - 2;
      float Pv = 0.f, Vv = 0.f;
      if ((unsigned)gh < (unsigned)IMG_H && (unsigned)gw < (unsigned)IMG_W) {
        int idx = ((b * NC + cgl) * IMG_H + gh) * IMG_W + gw;
        float dv = dp[idx], cdv = cdp[idx], gxv = gxp[idx], cgv = cgxp[idx];
        // d_left = d with last col zeroed; d_right = d with first col zeroed
        float dl  = (gw == IMG_W - 1) ? 0.f : dv;
        float cdl = (gw == IMG_W - 1) ? 0.f : cdv;
        float dr  = (gw == 0) ? 0.f : dv;
        float cdr = (gw == 0) ? 0.f : cdv;
        float cfd = cdl * cdr;                                      // cgx_from_ds
        float height = (cdl * dl + cdr * dr) * rcpf_(cdl + cdr + EPSV);
        float gfd = (dr - dl) * 0.5f * rcpf_(height + EPSV);        // gx_from_ds
        float wpc = ws[cgl];
        float den = fmaf(wpc, cgv, cfd);                            // wp*cgx + cgx_from_ds
        float num = fmaf(wpc * cgv, gxv, cfd * gfd);
        float gprop = num * rcpf_(den + EPSV);
        float cprop = den * rcpf_(wpc + 1.0f);
        Pv = cprop;
        Vv = cprop * gprop;
      }
      Pbuf[i] = Pv;
      Vbuf[i] = Vv;
    }
    __syncthreads();
    // ---- depthwise 5x5 conv of (P, V), 8 outputs along w per thread ----
    {
      int cgl = g * CG + clt;
      float sww[25];
      #pragma unroll
      for (int k2 = 0; k2 < 25; ++k2) sww[k2] = swp[cgl * 25 + k2];
      float den8[8], nom8[8];
      #pragma unroll
      for (int j = 0; j < 8; ++j) { den8[j] = 0.f; nom8[j] = 0.f; }
      #pragma unroll
      for (int kr = 0; kr < 5; ++kr) {
        int base = clt * (RH * RW) + (hh + kr) * RW + w0;  // 16B aligned
        const float4* p4 = (const float4*)&Pbuf[base];
        const float4* v4 = (const float4*)&Vbuf[base];
        float4 pa = p4[0], pb = p4[1], pc = p4[2];
        float4 va = v4[0], vb = v4[1], vc = v4[2];
        float pr[12] = {pa.x, pa.y, pa.z, pa.w, pb.x, pb.y, pb.z, pb.w,
                        pc.x, pc.y, pc.z, pc.w};
        float vr[12] = {va.x, va.y, va.z, va.w, vb.x, vb.y, vb.z, vb.w,
                        vc.x, vc.y, vc.z, vc.w};
        #pragma unroll
        for (int kc = 0; kc < 5; ++kc) {
          float wv = sww[kr * 5 + kc];
          #pragma unroll
          for (int j = 0; j < 8; ++j) {
            den8[j] = fmaf(wv, pr[kc + j], den8[j]);
            nom8[j] = fmaf(wv, vr[kc + j], nom8[j]);
          }
        }
      }
      float s0[8], u0[8];
      #pragma unroll
      for (int j = 0; j < 8; ++j) {
        float dw = den8[j];
        float s = dw * inv_Ssw;                 // cgx_s
        float gxs = nom8[j] * rcpf_(dw + EPSV); // gx_s
        s0[j] = s;
        u0[j] = s * gxs;                        // cgx_s*gx_s
      }
      int pbase = cgl * NPX + hh * TW + w0;     // 16B aligned
      float4* s4 = (float4*)&Sarr[pbase];
      float4* u4 = (float4*)&Uarr[pbase];
      s4[0] = make_float4(s0[0], s0[1], s0[2], s0[3]);
      s4[1] = make_float4(s0[4], s0[5], s0[6], s0[7]);
      u4[0] = make_float4(u0[0], u0[1], u0[2], u0[3]);
      u4[1] = make_float4(u0[4], u0[5], u0[6], u0[7]);
    }
  }
  __syncthreads();
  // ---- 1x1 channel matvec: thread = (px, o-half); half wave-uniform -> s_load cw ----
  const int wave = __builtin_amdgcn_readfirstlane(t >> 6);
  const int lane = t & 63;
  const int px = lane + (wave & 1) * 64;
  const int half = wave >> 1;  // SGPR-uniform
  float accn[16], accd[16];
  #pragma unroll
  for (int o = 0; o < 16; ++o) { accn[o] = 0.f; accd[o] = 0.f; }
  #pragma unroll
  for (int c = 0; c < NC; ++c) {
    float u = Uarr[c * NPX + px];
    float s = Sarr[c * NPX + px];
    const float* wrow = cwT + c * NO + half * 16;  // uniform address -> s_load
    #pragma unroll
    for (int o = 0; o < 16; ++o) {
      float wv = wrow[o];
      accn[o] = fmaf(wv, u, accn[o]);
      accd[o] = fmaf(wv, s, accd[o]);
    }
  }
  const int hl = px >> 4;  // TW == 16
  const int wl = px & 15;
  const int gh = h0 + hl, gw = w0t + wl;
  #pragma unroll
  for (int o = 0; o < 16; ++o) {
    int og = half * 16 + o;
    float dsum = accd[o];
    float gout = fmaf(accn[o], rcpf_(dsum + EPSV), bias[og]);
    int oidx = ((b * NO + og) * IMG_H + gh) * IMG_W + gw;
    out[oidx] = gout;                             // gx_out * STRIDE (=1)
    out[NB * NO * IMG_H * IMG_W + oidx] = dsum * inv_Scw;  // cgx_out
  }
}

extern "C" void kernel_launch(void* const* d_in, const int* in_sizes, int n_in,
                              void* d_out, int out_size, void* d_ws, size_t ws_size,
                              hipStream_t stream) {
  const float* dp   = (const float*)d_in[0];
  const float* cdp  = (const float*)d_in[1];
  const float* gxp  = (const float*)d_in[2];
  const float* cgxp = (const float*)d_in[3];
  const float* wp   = (const float*)d_in[4];
  const float* sw   = (const float*)d_in[5];
  const float* cw   = (const float*)d_in[6];
  const float* bias = (const float*)d_in[7];
  float* out = (float*)d_out;
  float* ws  = (float*)d_ws;

  weights_kernel<<<1, 256, 0, stream>>>(wp, sw, cw, ws);
  dim3 grid(IMG_W / TW, IMG_H / TH, NB);
  fused_kernel<<<grid, 256, 0, stream>>>(dp, cdp, gxp, cgxp, ws, bias, out);
}

// Round 2
// 422.545 us; speedup vs baseline: 1.2238x; 1.2238x over previous
//
#include <hip/hip_runtime.h>
#include <math.h>

// Problem constants (reference: B=8, C=32, O=32, H=256, W=256, K=5, pad=2)
constexpr int IMG_H = 256;
constexpr int IMG_W = 256;
constexpr int NB = 8;
constexpr int NC = 32;
constexpr int NO = 32;
constexpr int PLANE = IMG_H * IMG_W;          // 65536
constexpr int HALF = NB * NC * PLANE;         // 16,777,216 floats (64 MB)

// Kernel A tiling: per-block = one (b, c, 64x64 tile), halo 2
constexpr int ATH = 64;
constexpr int ATW = 64;
constexpr int ARH = ATH + 4;  // 68
constexpr int ARW = ATW + 4;  // 68
constexpr int AREG = ARH * ARW;  // 4624

#define EPSV 1e-20f

__device__ __forceinline__ float rcpf_(float x) { return __builtin_amdgcn_rcpf(x); }
__device__ __forceinline__ float softplusf_(float x) {
  return fmaxf(x, 0.0f) + log1pf(expf(-fabsf(x)));
}

// ws layout (floats): [0..31] wp, [32..831] sw (c-major, 25/ch),
// [832..1855] cwT[c][o] (transposed), [1856] sum(sw), [1857] sum(cw)
__global__ void weights_kernel(const float* __restrict__ wp_raw,
                               const float* __restrict__ sw_raw,
                               const float* __restrict__ cw_raw,
                               float* __restrict__ ws) {
  __shared__ float red[256];
  const int t = threadIdx.x;
  if (t < 32) ws[t] = softplusf_(wp_raw[t]);
  float ssum = 0.f;
  for (int i = t; i < NC * 25; i += 256) {
    float v = softplusf_(sw_raw[i]);
    ws[32 + i] = v;
    ssum += v;
  }
  float csum = 0.f;
  for (int i = t; i < NO * NC; i += 256) {
    float v = softplusf_(cw_raw[i]);
    int o = i >> 5, c = i & 31;
    ws[832 + c * NO + o] = v;  // transposed: [c][o]
    csum += v;
  }
  red[t] = ssum; __syncthreads();
  for (int off = 128; off; off >>= 1) { if (t < off) red[t] += red[t + off]; __syncthreads(); }
  const float S_sw = red[0];
  __syncthreads();
  red[t] = csum; __syncthreads();
  for (int off = 128; off; off >>= 1) { if (t < off) red[t] += red[t + off]; __syncthreads(); }
  if (t == 0) { ws[1856] = S_sw; ws[1857] = red[0]; }
}

// ---------------------------------------------------------------------------
// Kernel A: pointwise gradient-propagation + depthwise 5x5 normalized conv.
// Writes S = cgx_s into d_out[0 .. HALF), U = cgx_s*gx_s into d_out[HALF .. 2*HALF).
// LDS 36,992 B -> 4 blocks/CU (16 waves/CU).
// ---------------------------------------------------------------------------
__global__ __launch_bounds__(256, 4) void kernelA(
    const float* __restrict__ dp, const float* __restrict__ cdp,
    const float* __restrict__ gxp, const float* __restrict__ cgxp,
    const float* __restrict__ ws, float* __restrict__ out) {
  __shared__ __align__(16) float Pbuf[AREG];  // cgx_prop
  __shared__ __align__(16) float Vbuf[AREG];  // cgx_prop * gx_prop

  const int t = threadIdx.x;
  const int tile = blockIdx.x;           // 16 tiles: 4x4
  const int c = blockIdx.y;
  const int b = blockIdx.z;
  const int h0 = (tile >> 2) * ATH;
  const int w0t = (tile & 3) * ATW;

  const float wpc = ws[c];
  const float inv_wp1 = rcpf_(wpc + 1.0f);
  const float inv_Ssw = rcpf_(ws[1856]);
  const int plane = (b * NC + c) * PLANE;

  // ---- stage pointwise P,V over 68x68 region (zero-padded) ----
  #pragma unroll 1
  for (int k = 0; k < 19; ++k) {
    int i = t + k * 256;
    if (i < AREG) {
      int rr = i / ARW;
      int col = i - rr * ARW;
      int gh = h0 + rr - 2;
      int gw = w0t + col - 2;
      float Pv = 0.f, Vv = 0.f;
      if ((unsigned)gh < (unsigned)IMG_H && (unsigned)gw < (unsigned)IMG_W) {
        int idx = plane + gh * IMG_W + gw;
        float dv = dp[idx], cdv = cdp[idx], gxv = gxp[idx], cgv = cgxp[idx];
        // d_left = d with last col zeroed; d_right = d with first col zeroed
        float dl  = (gw == IMG_W - 1) ? 0.f : dv;
        float cdl = (gw == IMG_W - 1) ? 0.f : cdv;
        float dr  = (gw == 0) ? 0.f : dv;
        float cdr = (gw == 0) ? 0.f : cdv;
        float cfd = cdl * cdr;                                      // cgx_from_ds
        float height = (cdl * dl + cdr * dr) * rcpf_(cdl + cdr + EPSV);
        float gfd = (dr - dl) * 0.5f * rcpf_(height + EPSV);        // gx_from_ds
        float den = fmaf(wpc, cgv, cfd);                            // wp*cgx + cgx_from_ds
        float num = fmaf(wpc * cgv, gxv, cfd * gfd);
        float gprop = num * rcpf_(den + EPSV);
        float cprop = den * inv_wp1;
        Pv = cprop;
        Vv = cprop * gprop;
      }
      Pbuf[i] = Pv;
      Vbuf[i] = Vv;
    }
  }

  // spatial weights for this channel
  float sww[25];
  #pragma unroll
  for (int k2 = 0; k2 < 25; ++k2) sww[k2] = ws[32 + c * 25 + k2];

  __syncthreads();

  // ---- depthwise 5x5 conv: 512 tasks (64 rows x 8 runs-of-8), 2 per thread ----
  #pragma unroll
  for (int j = 0; j < 2; ++j) {
    int tau = t + j * 256;
    int row = tau >> 3;
    int w0l = (tau & 7) * 8;
    float den8[8], nom8[8];
    #pragma unroll
    for (int q = 0; q < 8; ++q) { den8[q] = 0.f; nom8[q] = 0.f; }
    #pragma unroll
    for (int kr = 0; kr < 5; ++kr) {
      int base = (row + kr) * ARW + w0l;  // 16B aligned (68r + 8k)
      const float4* p4 = (const float4*)&Pbuf[base];
      const float4* v4 = (const float4*)&Vbuf[base];
      float4 pa = p4[0], pb = p4[1], pc = p4[2];
      float4 va = v4[0], vb = v4[1], vc = v4[2];
      float pr[12] = {pa.x, pa.y, pa.z, pa.w, pb.x, pb.y, pb.z, pb.w,
                      pc.x, pc.y, pc.z, pc.w};
      float vr[12] = {va.x, va.y, va.z, va.w, vb.x, vb.y, vb.z, vb.w,
                      vc.x, vc.y, vc.z, vc.w};
      #pragma unroll
      for (int kc = 0; kc < 5; ++kc) {
        float wv = sww[kr * 5 + kc];
        #pragma unroll
        for (int q = 0; q < 8; ++q) {
          den8[q] = fmaf(wv, pr[kc + q], den8[q]);
          nom8[q] = fmaf(wv, vr[kc + q], nom8[q]);
        }
      }
    }
    float s0[8], u0[8];
    #pragma unroll
    for (int q = 0; q < 8; ++q) {
      float dw = den8[q];
      float s = dw * inv_Ssw;                 // cgx_s
      float gxs = nom8[q] * rcpf_(dw + EPSV); // gx_s
      s0[q] = s;
      u0[q] = s * gxs;
    }
    int gidx = plane + (h0 + row) * IMG_W + w0t + w0l;  // 32B aligned
    float4* sg = (float4*)&out[gidx];
    float4* ug = (float4*)&out[HALF + gidx];
    sg[0] = make_float4(s0[0], s0[1], s0[2], s0[3]);
    sg[1] = make_float4(s0[4], s0[5], s0[6], s0[7]);
    ug[0] = make_float4(u0[0], u0[1], u0[2], u0[3]);
    ug[1] = make_float4(u0[4], u0[5], u0[6], u0[7]);
  }
}

// ---------------------------------------------------------------------------
// Kernel B: 1x1 channel normalized conv, in-place on d_out.
// Reads S (first half) and U (second half) for its 256 block-private pixels,
// then overwrites them with gx_out / cgx_out. Barrier between reads & writes.
// Thread = (wave og in [0,4): 8 outputs) x (lane: 4 consecutive pixels).
// ---------------------------------------------------------------------------
__global__ __launch_bounds__(256, 4) void kernelB(
    float* __restrict__ out, const float* __restrict__ ws,
    const float* __restrict__ bias) {
  __shared__ __align__(16) float wlds[NC * NO];  // cwT [c][o]
  __shared__ float blds[NO];

  const int t = threadIdx.x;
  ((float4*)wlds)[t] = ((const float4*)(ws + 832))[t];  // 256*4 = 1024 floats
  if (t < NO) blds[t] = bias[t];
  const float inv_Scw = rcpf_(ws[1857]);
  __syncthreads();

  const int og = __builtin_amdgcn_readfirstlane(t >> 6);  // wave-uniform
  const int lane = t & 63;
  const int b = blockIdx.y;
  const int hw = blockIdx.x * 256 + lane * 4;
  const int idx0 = b * NC * PLANE + hw;

  float4 accn[8], accd[8];
  #pragma unroll
  for (int o = 0; o < 8; ++o) {
    accn[o] = make_float4(0.f, 0.f, 0.f, 0.f);
    accd[o] = make_float4(0.f, 0.f, 0.f, 0.f);
  }

  #pragma unroll 4
  for (int c = 0; c < NC; ++c) {
    const float4 s4 = *(const float4*)&out[idx0 + c * PLANE];
    const float4 u4 = *(const float4*)&out[HALF + idx0 + c * PLANE];
    const float* w8 = &wlds[c * NO + og * 8];
    #pragma unroll
    for (int o = 0; o < 8; ++o) {
      float wv = w8[o];
      accn[o].x = fmaf(wv, u4.x, accn[o].x);
      accn[o].y = fmaf(wv, u4.y, accn[o].y);
      accn[o].z = fmaf(wv, u4.z, accn[o].z);
      accn[o].w = fmaf(wv, u4.w, accn[o].w);
      accd[o].x = fmaf(wv, s4.x, accd[o].x);
      accd[o].y = fmaf(wv, s4.y, accd[o].y);
      accd[o].z = fmaf(wv, s4.z, accd[o].z);
      accd[o].w = fmaf(wv, s4.w, accd[o].w);
    }
  }

  __syncthreads();  // all reads in block done before any in-place write

  #pragma unroll
  for (int o = 0; o < 8; ++o) {
    int oo = og * 8 + o;
    float bv = blds[oo];
    float4 dn = accd[o];
    float4 g, cg;
    g.x = fmaf(accn[o].x, rcpf_(dn.x + EPSV), bv);
    g.y = fmaf(accn[o].y, rcpf_(dn.y + EPSV), bv);
    g.z = fmaf(accn[o].z, rcpf_(dn.z + EPSV), bv);
    g.w = fmaf(accn[o].w, rcpf_(dn.w + EPSV), bv);
    cg.x = dn.x * inv_Scw; cg.y = dn.y * inv_Scw;
    cg.z = dn.z * inv_Scw; cg.w = dn.w * inv_Scw;
    int oidx = (b * NO + oo) * PLANE + hw;
    *(float4*)&out[oidx] = g;
    *(float4*)&out[HALF + oidx] = cg;
  }
}

extern "C" void kernel_launch(void* const* d_in, const int* in_sizes, int n_in,
                              void* d_out, int out_size, void* d_ws, size_t ws_size,
                              hipStream_t stream) {
  const float* dp   = (const float*)d_in[0];
  const float* cdp  = (const float*)d_in[1];
  const float* gxp  = (const float*)d_in[2];
  const float* cgxp = (const float*)d_in[3];
  const float* wp   = (const float*)d_in[4];
  const float* sw   = (const float*)d_in[5];
  const float* cw   = (const float*)d_in[6];
  const float* bias = (const float*)d_in[7];
  float* out = (float*)d_out;
  float* ws  = (float*)d_ws;

  weights_kernel<<<1, 256, 0, stream>>>(wp, sw, cw, ws);
  kernelA<<<dim3(16, NC, NB), 256, 0, stream>>>(dp, cdp, gxp, cgxp, ws, out);
  kernelB<<<dim3(PLANE / 256, NB), 256, 0, stream>>>(out, ws, bias);
}

// Round 3
// 419.640 us; speedup vs baseline: 1.2322x; 1.0069x over previous
//
#include <hip/hip_runtime.h>
#include <math.h>

// Problem constants (reference: B=8, C=32, O=32, H=256, W=256, K=5, pad=2)
constexpr int IMG_H = 256;
constexpr int IMG_W = 256;
constexpr int NB = 8;
constexpr int NC = 32;
constexpr int NO = 32;
constexpr int PLANE = IMG_H * IMG_W;          // 65536
constexpr int HALF = NB * NC * PLANE;         // 16,777,216 floats (64 MB)

// Kernel A tiling: per-block = one (b, c, 64x64 tile), halo 2
constexpr int ATH = 64;
constexpr int ATW = 64;
constexpr int ARH = ATH + 4;  // 68
constexpr int ARW = ATW + 4;  // 68
constexpr int AREG = ARH * ARW;  // 4624 = 18*256 + 16

#define EPSV 1e-20f

__device__ __forceinline__ float rcpf_(float x) { return __builtin_amdgcn_rcpf(x); }
__device__ __forceinline__ float softplusf_(float x) {
  return fmaxf(x, 0.0f) + log1pf(expf(-fabsf(x)));
}

// ws layout (floats): [0..31] wp, [32..831] sw (c-major, 25/ch),
// [832..1855] cwT[c][o] (transposed), [1856] sum(sw), [1857] sum(cw)
__global__ void weights_kernel(const float* __restrict__ wp_raw,
                               const float* __restrict__ sw_raw,
                               const float* __restrict__ cw_raw,
                               float* __restrict__ ws) {
  __shared__ float red[256];
  const int t = threadIdx.x;
  if (t < 32) ws[t] = softplusf_(wp_raw[t]);
  float ssum = 0.f;
  for (int i = t; i < NC * 25; i += 256) {
    float v = softplusf_(sw_raw[i]);
    ws[32 + i] = v;
    ssum += v;
  }
  float csum = 0.f;
  for (int i = t; i < NO * NC; i += 256) {
    float v = softplusf_(cw_raw[i]);
    int o = i >> 5, c = i & 31;
    ws[832 + c * NO + o] = v;  // transposed: [c][o]
    csum += v;
  }
  red[t] = ssum; __syncthreads();
  for (int off = 128; off; off >>= 1) { if (t < off) red[t] += red[t + off]; __syncthreads(); }
  const float S_sw = red[0];
  __syncthreads();
  red[t] = csum; __syncthreads();
  for (int off = 128; off; off >>= 1) { if (t < off) red[t] += red[t + off]; __syncthreads(); }
  if (t == 0) { ws[1856] = S_sw; ws[1857] = red[0]; }
}

// Pointwise gradient-propagation math. Requires cdv/cgv pre-zeroed for
// OOB pixels (then Pv = Vv = 0 follows algebraically, no NaN).
__device__ __forceinline__ void pointwise_pv(
    float dv, float cdv, float gxv, float cgv, int gw,
    float wpc, float inv_wp1, float& Pv, float& Vv) {
  // d_left = d with last col zeroed; d_right = d with first col zeroed
  float dl  = (gw == IMG_W - 1) ? 0.f : dv;
  float cdl = (gw == IMG_W - 1) ? 0.f : cdv;
  float dr  = (gw == 0) ? 0.f : dv;
  float cdr = (gw == 0) ? 0.f : cdv;
  float cfd = cdl * cdr;                                      // cgx_from_ds
  float height = (cdl * dl + cdr * dr) * rcpf_(cdl + cdr + EPSV);
  float gfd = (dr - dl) * 0.5f * rcpf_(height + EPSV);        // gx_from_ds
  float den = fmaf(wpc, cgv, cfd);                            // wp*cgx + cgx_from_ds
  float num = fmaf(wpc * cgv, gxv, cfd * gfd);
  float gprop = num * rcpf_(den + EPSV);
  float cprop = den * inv_wp1;
  Pv = cprop;
  Vv = cprop * gprop;
}

// ---------------------------------------------------------------------------
// Kernel A: pointwise gradient-propagation + depthwise 5x5 normalized conv.
// Writes S = cgx_s into out[0 .. HALF), U = cgx_s*gx_s into out[HALF .. 2*HALF).
// Staging is phase-split (9 region elements loaded per batch -> 36 global
// loads in flight per wave) and branch-free (clamped addresses + select).
// LDS 36,992 B -> 4 blocks/CU (16 waves/CU).
// ---------------------------------------------------------------------------
__global__ __launch_bounds__(256, 4) void kernelA(
    const float* __restrict__ dp, const float* __restrict__ cdp,
    const float* __restrict__ gxp, const float* __restrict__ cgxp,
    const float* __restrict__ ws, float* __restrict__ out) {
  __shared__ __align__(16) float Pbuf[AREG];  // cgx_prop
  __shared__ __align__(16) float Vbuf[AREG];  // cgx_prop * gx_prop

  const int t = threadIdx.x;
  const int tile = blockIdx.x;           // 16 tiles: 4x4
  const int c = blockIdx.y;
  const int b = blockIdx.z;
  const int h0 = (tile >> 2) * ATH;
  const int w0t = (tile & 3) * ATW;

  const float wpc = ws[c];
  const float inv_wp1 = rcpf_(wpc + 1.0f);
  const float inv_Ssw = rcpf_(ws[1856]);
  const int plane = (b * NC + c) * PLANE;

  // ---- stage pointwise P,V over 68x68 region, 2 chunks of 9 + tail ----
  #pragma unroll 1
  for (int chunk = 0; chunk < 2; ++chunk) {
    float rd[9], rc[9], rg[9], rcg[9], rm[9];
    int rgw[9];
    #pragma unroll
    for (int k = 0; k < 9; ++k) {
      int i = t + (chunk * 9 + k) * 256;
      int rr = i / ARW;
      int col = i - rr * ARW;
      int gh = h0 + rr - 2;
      int gw = w0t + col - 2;
      bool inb = ((unsigned)gh < (unsigned)IMG_H) & ((unsigned)gw < (unsigned)IMG_W);
      int ghc = min(max(gh, 0), IMG_H - 1);
      int gwc = min(max(gw, 0), IMG_W - 1);
      int idx = plane + ghc * IMG_W + gwc;
      rd[k] = dp[idx];
      rc[k] = cdp[idx];
      rg[k] = gxp[idx];
      rcg[k] = cgxp[idx];
      rm[k] = inb ? 1.0f : 0.0f;
      rgw[k] = gw;
    }
    #pragma unroll
    for (int k = 0; k < 9; ++k) {
      int i = t + (chunk * 9 + k) * 256;
      float Pv, Vv;
      pointwise_pv(rd[k], rc[k] * rm[k], rg[k], rcg[k] * rm[k], rgw[k],
                   wpc, inv_wp1, Pv, Vv);
      Pbuf[i] = Pv;
      Vbuf[i] = Vv;
    }
  }
  if (t < 16) {  // tail: elements 4608..4623
    int i = t + 18 * 256;
    int rr = i / ARW;
    int col = i - rr * ARW;
    int gh = h0 + rr - 2;
    int gw = w0t + col - 2;
    bool inb = ((unsigned)gh < (unsigned)IMG_H) & ((unsigned)gw < (unsigned)IMG_W);
    int ghc = min(max(gh, 0), IMG_H - 1);
    int gwc = min(max(gw, 0), IMG_W - 1);
    int idx = plane + ghc * IMG_W + gwc;
    float m = inb ? 1.0f : 0.0f;
    float Pv, Vv;
    pointwise_pv(dp[idx], cdp[idx] * m, gxp[idx], cgxp[idx] * m, gw,
                 wpc, inv_wp1, Pv, Vv);
    Pbuf[i] = Pv;
    Vbuf[i] = Vv;
  }

  // spatial weights for this channel
  float sww[25];
  #pragma unroll
  for (int k2 = 0; k2 < 25; ++k2) sww[k2] = ws[32 + c * 25 + k2];

  __syncthreads();

  // ---- depthwise 5x5 conv: 512 tasks (64 rows x 8 runs-of-8), 2 per thread ----
  #pragma unroll
  for (int j = 0; j < 2; ++j) {
    int tau = t + j * 256;
    int row = tau >> 3;
    int w0l = (tau & 7) * 8;
    float den8[8], nom8[8];
    #pragma unroll
    for (int q = 0; q < 8; ++q) { den8[q] = 0.f; nom8[q] = 0.f; }
    #pragma unroll
    for (int kr = 0; kr < 5; ++kr) {
      int base = (row + kr) * ARW + w0l;  // 16B aligned (68r + 8k)
      const float4* p4 = (const float4*)&Pbuf[base];
      const float4* v4 = (const float4*)&Vbuf[base];
      float4 pa = p4[0], pb = p4[1], pc = p4[2];
      float4 va = v4[0], vb = v4[1], vc = v4[2];
      float pr[12] = {pa.x, pa.y, pa.z, pa.w, pb.x, pb.y, pb.z, pb.w,
                      pc.x, pc.y, pc.z, pc.w};
      float vr[12] = {va.x, va.y, va.z, va.w, vb.x, vb.y, vb.z, vb.w,
                      vc.x, vc.y, vc.z, vc.w};
      #pragma unroll
      for (int kc = 0; kc < 5; ++kc) {
        float wv = sww[kr * 5 + kc];
        #pragma unroll
        for (int q = 0; q < 8; ++q) {
          den8[q] = fmaf(wv, pr[kc + q], den8[q]);
          nom8[q] = fmaf(wv, vr[kc + q], nom8[q]);
        }
      }
    }
    float s0[8], u0[8];
    #pragma unroll
    for (int q = 0; q < 8; ++q) {
      float dw = den8[q];
      float s = dw * inv_Ssw;                 // cgx_s
      float gxs = nom8[q] * rcpf_(dw + EPSV); // gx_s
      s0[q] = s;
      u0[q] = s * gxs;
    }
    int gidx = plane + (h0 + row) * IMG_W + w0t + w0l;  // 32B aligned
    float4* sg = (float4*)&out[gidx];
    float4* ug = (float4*)&out[HALF + gidx];
    sg[0] = make_float4(s0[0], s0[1], s0[2], s0[3]);
    sg[1] = make_float4(s0[4], s0[5], s0[6], s0[7]);
    ug[0] = make_float4(u0[0], u0[1], u0[2], u0[3]);
    ug[1] = make_float4(u0[4], u0[5], u0[6], u0[7]);
  }
}

// ---------------------------------------------------------------------------
// Kernel B: 1x1 channel normalized conv, in-place on d_out.
// Reads S (first half) and U (second half) for its 256 block-private pixels,
// then overwrites them with gx_out / cgx_out. Barrier between reads & writes.
// Thread = (wave og in [0,4): 8 outputs) x (lane: 4 consecutive pixels).
// ---------------------------------------------------------------------------
__global__ __launch_bounds__(256, 4) void kernelB(
    float* __restrict__ out, const float* __restrict__ ws,
    const float* __restrict__ bias) {
  __shared__ __align__(16) float wlds[NC * NO];  // cwT [c][o]
  __shared__ float blds[NO];

  const int t = threadIdx.x;
  ((float4*)wlds)[t] = ((const float4*)(ws + 832))[t];  // 256*4 = 1024 floats
  if (t < NO) blds[t] = bias[t];
  const float inv_Scw = rcpf_(ws[1857]);
  __syncthreads();

  const int og = __builtin_amdgcn_readfirstlane(t >> 6);  // wave-uniform
  const int lane = t & 63;
  const int b = blockIdx.y;
  const int hw = blockIdx.x * 256 + lane * 4;
  const int idx0 = b * NC * PLANE + hw;

  float4 accn[8], accd[8];
  #pragma unroll
  for (int o = 0; o < 8; ++o) {
    accn[o] = make_float4(0.f, 0.f, 0.f, 0.f);
    accd[o] = make_float4(0.f, 0.f, 0.f, 0.f);
  }

  #pragma unroll 8
  for (int c = 0; c < NC; ++c) {
    const float4 s4 = *(const float4*)&out[idx0 + c * PLANE];
    const float4 u4 = *(const float4*)&out[HALF + idx0 + c * PLANE];
    const float* w8 = &wlds[c * NO + og * 8];
    #pragma unroll
    for (int o = 0; o < 8; ++o) {
      float wv = w8[o];
      accn[o].x = fmaf(wv, u4.x, accn[o].x);
      accn[o].y = fmaf(wv, u4.y, accn[o].y);
      accn[o].z = fmaf(wv, u4.z, accn[o].z);
      accn[o].w = fmaf(wv, u4.w, accn[o].w);
      accd[o].x = fmaf(wv, s4.x, accd[o].x);
      accd[o].y = fmaf(wv, s4.y, accd[o].y);
      accd[o].z = fmaf(wv, s4.z, accd[o].z);
      accd[o].w = fmaf(wv, s4.w, accd[o].w);
    }
  }

  __syncthreads();  // all reads in block done before any in-place write

  #pragma unroll
  for (int o = 0; o < 8; ++o) {
    int oo = og * 8 + o;
    float bv = blds[oo];
    float4 dn = accd[o];
    float4 g, cg;
    g.x = fmaf(accn[o].x, rcpf_(dn.x + EPSV), bv);
    g.y = fmaf(accn[o].y, rcpf_(dn.y + EPSV), bv);
    g.z = fmaf(accn[o].z, rcpf_(dn.z + EPSV), bv);
    g.w = fmaf(accn[o].w, rcpf_(dn.w + EPSV), bv);
    cg.x = dn.x * inv_Scw; cg.y = dn.y * inv_Scw;
    cg.z = dn.z * inv_Scw; cg.w = dn.w * inv_Scw;
    int oidx = (b * NO + oo) * PLANE + hw;
    *(float4*)&out[oidx] = g;
    *(float4*)&out[HALF + oidx] = cg;
  }
}

extern "C" void kernel_launch(void* const* d_in, const int* in_sizes, int n_in,
                              void* d_out, int out_size, void* d_ws, size_t ws_size,
                              hipStream_t stream) {
  const float* dp   = (const float*)d_in[0];
  const float* cdp  = (const float*)d_in[1];
  const float* gxp  = (const float*)d_in[2];
  const float* cgxp = (const float*)d_in[3];
  const float* wp   = (const float*)d_in[4];
  const float* sw   = (const float*)d_in[5];
  const float* cw   = (const float*)d_in[6];
  const float* bias = (const float*)d_in[7];
  float* out = (float*)d_out;
  float* ws  = (float*)d_ws;

  weights_kernel<<<1, 256, 0, stream>>>(wp, sw, cw, ws);
  kernelA<<<dim3(16, NC, NB), 256, 0, stream>>>(dp, cdp, gxp, cgxp, ws, out);
  kernelB<<<dim3(PLANE / 256, NB), 256, 0, stream>>>(out, ws, bias);
}